// Round 1
// 137.256 us; speedup vs baseline: 1.0117x; 1.0117x over previous
//
#include <hip/hip_runtime.h>
#include <math.h>

// Geometry fixed by reference: (B=2, T=20, H=480, W=480)
#define TS   20
#define NL   5
#define NS   26    // [0..4]=hits [5..9]=p_tot [10..14]=t_tot [15..19]=mae_cum [20]=anti_cnt [21..25]=Sp,St,Spt,Spp,Stt
#define GX   45
#define TPB  256
#define F4PT 5     // float4 per thread: 45*256*5 = 57600 exactly
#define HW4  57600
#define WCH  (F4PT * 64)   // float4 per wave chunk (wave-contiguous layout)

// thresholds mapped to normalized space: p >= thr  <=>  pn >= ln(thr+1)/ln(31)
constexpr float C1 = (float)(0.09531017980432486 / 3.4339872044851463);
constexpr float C2 = (float)(0.69314718055994531 / 3.4339872044851463);
constexpr float C3 = (float)(1.09861228866810969 / 3.4339872044851463);
constexpr float C4 = (float)(1.79175946922805500 / 3.4339872044851463);
constexpr float C5 = (float)(2.19722457733621938 / 3.4339872044851463);

__device__ __forceinline__ float expm1_ln31(float x)   // exp(x*ln31) - 1, x in [0,1)
{
#if __has_builtin(__builtin_amdgcn_exp2f)
    return __builtin_amdgcn_exp2f(x * 4.9541963103868751f) - 1.0f;  // ln(31)*log2(e)
#else
    return __expf(x * 3.4339872044851463f) - 1.0f;
#endif
}

__device__ __forceinline__ void px(float pn, float tn, float mn,
    unsigned& pP, unsigned& tP, unsigned& hP, float cum[NL],
    float& sp, float& st, float& spt, float& spp, float& stt)
{
    bool mok = mn > 0.5f;
    float pm = mok ? pn : -1.0f;                // fold mask: all compares fail when masked out
    float qm = mok ? tn : -1.0f;
    bool p1 = pm >= C1, p2 = pm >= C2, p3 = pm >= C3, p4 = pm >= C4, p5 = pm >= C5;
    bool q1 = qm >= C1, q2 = qm >= C2, q3 = qm >= C3, q4 = qm >= C4, q5 = qm >= C5;
    int lp = (int)p1 + (int)p2 + (int)p3 + (int)p4 + (int)p5;   // 0..5; 0 = below thr[0] or masked
    int lq = (int)q1 + (int)q2 + (int)q3 + (int)q4 + (int)q5;
    unsigned op = 1u << (5 * lp);
    unsigned ot = 1u << (5 * lq);
    unsigned h  = op & ot;          // field l counts lp==lq==l; field 0 = masked-or-double-zero (anti-cnt)
    pP += op;  tP += ot;  hP += h;
    float p = expm1_ln31(pn);                   // physical values only feed moments / |p-q|
    float q = expm1_ln31(tn);
    bool keep = (h & 1u) == 0u;                 // mask && !(double-zero)
    float pz = keep ? p : 0.0f;
    float qz = keep ? q : 0.0f;
    sp += pz;  st += qz;
    spt = fmaf(pz, qz, spt);
    spp = fmaf(pz, pz, spp);
    stt = fmaf(qz, qz, stt);
    float ad = fabsf(p - q);
    cum[0] += q1 ? ad : 0.0f;                   // cumulative: mae_num[l] = cum[l] - cum[l+1]
    cum[1] += q2 ? ad : 0.0f;
    cum[2] += q3 ? ad : 0.0f;
    cum[3] += q4 ? ad : 0.0f;
    cum[4] += q5 ? ad : 0.0f;
}

__global__ __launch_bounds__(TPB) void metscore_pass1(
    const float4* __restrict__ pred, const float4* __restrict__ targ,
    const float4* __restrict__ mask, float* __restrict__ sums /* [TS][NS] */)
{
    const int t = blockIdx.y;
    const int b = blockIdx.z;
    const int lane = threadIdx.x & 63;
    const int wv   = (blockIdx.x << 2) + (threadIdx.x >> 6);   // wave index within (b,t): 0..179
    // wave-contiguous chunks: lane l, sub-iter j reads base + j*64 -> byte offsets j*1024
    const size_t base = ((size_t)b * TS + t) * (size_t)HW4
                      + (size_t)wv * WCH + lane;

    // Deep staging, pinned with sched_barrier(0) so the scheduler cannot sink
    // the loads back to their uses (which is what collapsed the previous
    // version to 32 VGPRs and a load->wait->use convoy).
    float4 pv[F4PT], tv[F4PT], mv[F4PT];
    #pragma unroll
    for (int j = 0; j < 3; ++j) {               // 9 loads in flight
        pv[j] = pred[base + j * 64];
        tv[j] = targ[base + j * 64];
        mv[j] = mask[base + j * 64];
    }
    __builtin_amdgcn_sched_barrier(0);

    unsigned pP = 0u, tP = 0u, hP = 0u;
    float cum[NL] = {0, 0, 0, 0, 0};
    float sp = 0, st = 0, spt = 0, spp = 0, stt = 0;

    // process j=0 while 6 younger loads remain outstanding
    px(pv[0].x, tv[0].x, mv[0].x, pP, tP, hP, cum, sp, st, spt, spp, stt);
    px(pv[0].y, tv[0].y, mv[0].y, pP, tP, hP, cum, sp, st, spt, spp, stt);
    px(pv[0].z, tv[0].z, mv[0].z, pP, tP, hP, cum, sp, st, spt, spp, stt);
    px(pv[0].w, tv[0].w, mv[0].w, pP, tP, hP, cum, sp, st, spt, spp, stt);
    __builtin_amdgcn_sched_barrier(0);

    #pragma unroll
    for (int j = 3; j < F4PT; ++j) {            // issue the last 6 loads
        pv[j] = pred[base + j * 64];
        tv[j] = targ[base + j * 64];
        mv[j] = mask[base + j * 64];
    }
    __builtin_amdgcn_sched_barrier(0);

    #pragma unroll
    for (int j = 1; j < F4PT; ++j) {
        px(pv[j].x, tv[j].x, mv[j].x, pP, tP, hP, cum, sp, st, spt, spp, stt);
        px(pv[j].y, tv[j].y, mv[j].y, pP, tP, hP, cum, sp, st, spt, spp, stt);
        px(pv[j].z, tv[j].z, mv[j].z, pP, tP, hP, cum, sp, st, spt, spp, stt);
        px(pv[j].w, tv[j].w, mv[j].w, pP, tP, hP, cum, sp, st, spt, spp, stt);
    }

    // drain one-hot packs (20 px < 31 field capacity) into 2x16-bit packed accumulators
    unsigned c16[8];
    #pragma unroll
    for (int k = 0; k < 8; ++k) c16[k] = 0u;
    #pragma unroll
    for (int l = 0; l < NL; ++l) {
        c16[l >> 1]        += ((hP >> (5 * (l + 1))) & 31u) << (16 * (l & 1));
        c16[(5 + l) >> 1]  += ((pP >> (5 * (l + 1))) & 31u) << (16 * ((5 + l) & 1));
        c16[(10 + l) >> 1] += ((tP >> (5 * (l + 1))) & 31u) << (16 * ((10 + l) & 1));
    }
    c16[7] += (hP & 31u) << 16;   // counter 15 = anti-cnt (masked-or-double-zero count)

    // wave(64) reduce: 8 packed u32 + 10 floats
    float f[10] = {cum[0], cum[1], cum[2], cum[3], cum[4], sp, st, spt, spp, stt};
    #pragma unroll
    for (int k = 0; k < 8; ++k) {
        unsigned x = c16[k];
        x += __shfl_down(x, 32); x += __shfl_down(x, 16); x += __shfl_down(x, 8);
        x += __shfl_down(x, 4);  x += __shfl_down(x, 2);  x += __shfl_down(x, 1);
        c16[k] = x;
    }
    #pragma unroll
    for (int k = 0; k < 10; ++k) {
        float x = f[k];
        x += __shfl_down(x, 32); x += __shfl_down(x, 16); x += __shfl_down(x, 8);
        x += __shfl_down(x, 4);  x += __shfl_down(x, 2);  x += __shfl_down(x, 1);
        f[k] = x;
    }

    __shared__ unsigned ldsU[4][8];
    __shared__ float    ldsF[4][10];
    const int wvb = threadIdx.x >> 6;
    if (lane == 0) {
        #pragma unroll
        for (int k = 0; k < 8; ++k) ldsU[wvb][k] = c16[k];
        #pragma unroll
        for (int k = 0; k < 10; ++k) ldsF[wvb][k] = f[k];
    }
    __syncthreads();
    if (threadIdx.x < 8) {
        unsigned s = ldsU[0][threadIdx.x] + ldsU[1][threadIdx.x]
                   + ldsU[2][threadIdx.x] + ldsU[3][threadIdx.x];
        int c0 = 2 * threadIdx.x, c1 = c0 + 1;          // counter indices
        int n0 = (c0 == 15) ? 20 : c0;                  // counter->NS slot (anti-cnt lives at 20)
        int n1 = (c1 == 15) ? 20 : c1;
        atomicAdd(&sums[t * NS + n0], (float)(s & 0xFFFFu));
        atomicAdd(&sums[t * NS + n1], (float)(s >> 16));
    } else if (threadIdx.x < 18) {
        int k = threadIdx.x - 8;                        // 0..4 cum -> 15..19, 5..9 moments -> 21..25
        float s = ldsF[0][k] + ldsF[1][k] + ldsF[2][k] + ldsF[3][k];
        int n = (k < 5) ? (15 + k) : (16 + k);
        atomicAdd(&sums[t * NS + n], s);
    }
}

// out layout: [0]=total [1..20]=score_time [21..40]=r_time [41..140]=ts_mat
//             [141..240]=mae_mat [241..245]=ts mean [246..250]=mae mean
__global__ __launch_bounds__(128) void metscore_final(
    const float* __restrict__ sums, float* __restrict__ out)
{
    __shared__ float ts_s[TS][NL];
    __shared__ float mae_s[TS][NL];
    __shared__ float sc_s[TS];
    const int tid = threadIdx.x;

    if (tid < TS * NL) {
        int tt_ = tid / NL, l = tid % NL;
        const float* s = sums + tt_ * NS;
        float h = s[l], pt = s[5 + l], tt = s[10 + l];
        float mn = s[15 + l] - ((l < NL - 1) ? s[16 + l] : 0.0f);   // telescoped mae_num
        float ts  = h / (pt + tt - h + 1e-8f);
        float mae = (tt > 0.0f) ? (mn / fmaxf(tt, 1.0f)) : 0.0f;
        ts_s[tt_][l]  = ts;
        mae_s[tt_][l] = mae;
        out[41 + tid]  = ts;
        out[141 + tid] = mae;
    }
    __syncthreads();

    if (tid < TS) {
        const float* s = sums + tid * NS;
        double cnt = 460800.0 - (double)s[20];   // cnt = B*H*W - anti_cnt
        double sp = s[21], st = s[22];
        double spt = s[23], spp = s[24], stt = s[25];
        double sc = fmax(cnt, 1.0);
        double pmn = sp / sc, tmn = st / sc;
        double num = spt - pmn * st - tmn * sp + pmn * tmn * cnt;
        double vp  = spp - 2.0 * pmn * sp + pmn * pmn * cnt;
        double vt  = stt - 2.0 * tmn * st + tmn * tmn * cnt;
        double r = num / (sqrt(vp * vt) + 1e-6);
        r = fmin(fmax(r, -1.0), 1.0);
        float rt = (cnt > 0.0) ? (float)r : 0.0f;
        out[21 + tid] = rt;

        const float LW[NL] = {0.1f, 0.1f, 0.2f, 0.25f, 0.35f};
        float term_corr = sqrtf(expf(rt - 1.0f));
        float accl = 0.0f;
        #pragma unroll
        for (int l = 0; l < NL; ++l)
            accl += LW[l] * ts_s[tid][l] * sqrtf(expf(-mae_s[tid][l] * 0.01f));
        float sct = term_corr * accl;
        out[1 + tid] = sct;

        const float TW[TS] = {0.0075f, 0.02f, 0.03f, 0.04f, 0.05f, 0.06f, 0.07f,
                              0.08f, 0.09f, 0.1f, 0.09f, 0.08f, 0.07f, 0.06f,
                              0.05f, 0.04f, 0.03f, 0.02f, 0.0075f, 0.005f};
        sc_s[tid] = sct * TW[tid];
    }
    __syncthreads();

    if (tid == 0) {
        float tot = 0.0f;
        for (int k = 0; k < TS; ++k) tot += sc_s[k];
        out[0] = tot;
    }
    if (tid < NL) {
        float a = 0.0f, bsum = 0.0f;
        for (int k = 0; k < TS; ++k) { a += ts_s[k][tid]; bsum += mae_s[k][tid]; }
        out[241 + tid] = a * (1.0f / TS);
        out[246 + tid] = bsum * (1.0f / TS);
    }
}

extern "C" void kernel_launch(void* const* d_in, const int* in_sizes, int n_in,
                              void* d_out, int out_size, void* d_ws, size_t ws_size,
                              hipStream_t stream) {
    (void)in_sizes; (void)n_in; (void)out_size; (void)ws_size;
    const float4* pred = (const float4*)d_in[0];
    const float4* targ = (const float4*)d_in[1];
    const float4* mask = (const float4*)d_in[2];
    float* out  = (float*)d_out;
    float* sums = (float*)d_ws;

    // ws is poisoned 0xAA before every launch — zero the accumulators
    hipMemsetAsync(sums, 0, TS * NS * sizeof(float), stream);

    dim3 grid(GX, TS, 2);   // 1800 blocks -> all co-resident at <=7 waves/SIMD
    metscore_pass1<<<grid, TPB, 0, stream>>>(pred, targ, mask, sums);
    metscore_final<<<1, 128, 0, stream>>>(sums, out);
}